// Round 4
// baseline (96002.454 us; speedup 1.0000x reference)
//
#include <hip/hip_runtime.h>
#include <math.h>

// BatchFrechetMean: inductive geodesic mean of 256 SPD 256x256 matrices.
// Eigh-free: fixed-interval Chebyshev polynomial evaluation of M^{-1/2} and S^t,
// persistent kernel + hand-rolled agent-scope grid barrier.
// R4: 256 blocks (all CUs), 4-wave K-split per 16x16 tile + LDS reduce,
// XCD-aware tile map, f_{k+1} prefetch to bf16 planes, NT out stores,
// cache-line-padded barrier counters (16 groups of 16).
//
// Spectral bounds (provable): lambda(f) in [1, ~5.2] => lambda(M) in [1, 5.5],
// lambda(S) in [1/5.75, 5.75]. Approximation intervals with margin:
//   x^{-1/2} on [0.95, 5.75], deg 11 (s=4, m=2)  -> err ~5e-5
//   x^{t}    on [0.17, 5.90], deg 39 (s=8, m=4)  -> err ~3e-5

#define NBLK 256
#define AM 0.95f
#define BM 5.75f
#define AS_ 0.17f
#define BS_ 5.90f

typedef __attribute__((ext_vector_type(8))) short bf16x8;
typedef __attribute__((ext_vector_type(4))) float f32x4;

enum {
  iXM = 0, iU2, iU4, iCBA, iCBB, iQM1, iQM0, iISQ, iSQ, iG,
  iXS, iV2, iV3, iV4, iV8, iSBA, iSBB, iSBC, iQS3, iQS2, iQS1, iQS0, iPP, iHH,
  iFK, NBUF
};

// Matrices stored as bf16 hi+lo planes (value = hi + lo, ~2^-16 rel err).
__device__ __align__(16) short gHi[NBUF][65536];
__device__ __align__(16) short gLo[NBUF][65536];
__device__ float g_aS[256][40];   // per-step regrouped Cheb coeffs of x^{t_k}
__device__ float g_aM[12];        // regrouped Cheb coeffs of x^{-1/2}

struct __align__(128) Ctr { int v; int pad[31]; };
__device__ Ctr g_c0[16];          // one cache line per group counter
__device__ Ctr g_c1;
__device__ int g_gen;

__device__ __forceinline__ short f2bf(float x) {
  unsigned u = __builtin_bit_cast(unsigned, x);
  unsigned r = (u + 0x7FFFu + ((u >> 16) & 1u)) >> 16;   // RNE to bf16
  return (short)(unsigned short)r;
}
__device__ __forceinline__ float bf2f(short h) {
  unsigned u = ((unsigned)(unsigned short)h) << 16;
  return __builtin_bit_cast(float, u);
}
__device__ __forceinline__ float rdm(int m, int idx) {
  return bf2f(gHi[m][idx]) + bf2f(gLo[m][idx]);
}
__device__ __forceinline__ void wrm(int m, int idx, float v) {
  short h = f2bf(v);
  gHi[m][idx] = h;
  gLo[m][idx] = f2bf(v - bf2f(h));
}

// Partial C(arow,bcol) of A*B over this wave's K-range (64 wide).
// B symmetric -> read B by rows. Split hi/lo bf16: 3 MFMAs per 32-chunk.
__device__ __forceinline__ f32x4 mm64(int Ai, int Bi, int arow, int bcol, int kbase) {
  f32x4 acc = {0.0f, 0.0f, 0.0f, 0.0f};
  const short* ah = gHi[Ai] + arow * 256 + kbase;
  const short* al = gLo[Ai] + arow * 256 + kbase;
  const short* bh = gHi[Bi] + bcol * 256 + kbase;
  const short* bl = gLo[Bi] + bcol * 256 + kbase;
#pragma unroll
  for (int k0 = 0; k0 < 64; k0 += 32) {
    bf16x8 Ah = *(const bf16x8*)(ah + k0);
    bf16x8 Al = *(const bf16x8*)(al + k0);
    bf16x8 Bh = *(const bf16x8*)(bh + k0);
    bf16x8 Bl = *(const bf16x8*)(bl + k0);
    acc = __builtin_amdgcn_mfma_f32_16x16x32_bf16(Ah, Bh, acc, 0, 0, 0);
    acc = __builtin_amdgcn_mfma_f32_16x16x32_bf16(Al, Bh, acc, 0, 0, 0);
    acc = __builtin_amdgcn_mfma_f32_16x16x32_bf16(Ah, Bl, acc, 0, 0, 0);
  }
  return acc;
}

__device__ __forceinline__ void putp(float (*P)[4][64][5], int m, int wave, int lane,
                                     f32x4 v) {
  P[m][wave][lane][0] = v[0];
  P[m][wave][lane][1] = v[1];
  P[m][wave][lane][2] = v[2];
  P[m][wave][lane][3] = v[3];
}
__device__ __forceinline__ float getp(float (*P)[4][64][5], int m, int lane, int w) {
  return P[m][0][lane][w] + P[m][1][lane][w] + P[m][2][lane][w] + P[m][3][lane][w];
}

// Two-level grid barrier: 16 groups of 16 (padded counters), agent scope.
__device__ __forceinline__ void gridbar(int bid, int* sgen) {
  __syncthreads();
  if (threadIdx.x == 0) {
    int g = *sgen;
    int grp = bid & 15;
    int v = __hip_atomic_fetch_add(&g_c0[grp].v, 1, __ATOMIC_ACQ_REL, __HIP_MEMORY_SCOPE_AGENT);
    if (v == 15) {
      __hip_atomic_store(&g_c0[grp].v, 0, __ATOMIC_RELAXED, __HIP_MEMORY_SCOPE_AGENT);
      int w = __hip_atomic_fetch_add(&g_c1.v, 1, __ATOMIC_ACQ_REL, __HIP_MEMORY_SCOPE_AGENT);
      if (w == 15) {
        __hip_atomic_store(&g_c1.v, 0, __ATOMIC_RELAXED, __HIP_MEMORY_SCOPE_AGENT);
        __hip_atomic_store(&g_gen, g + 1, __ATOMIC_RELEASE, __HIP_MEMORY_SCOPE_AGENT);
      } else {
        while (__hip_atomic_load(&g_gen, __ATOMIC_ACQUIRE, __HIP_MEMORY_SCOPE_AGENT) <= g)
          __builtin_amdgcn_s_sleep(2);
      }
    } else {
      while (__hip_atomic_load(&g_gen, __ATOMIC_ACQUIRE, __HIP_MEMORY_SCOPE_AGENT) <= g)
        __builtin_amdgcn_s_sleep(2);
    }
    *sgen = g + 1;
  }
  __syncthreads();
}

// Chebyshev-PS regrouping: p = sum_j c_j T_j  ->  sum_i q_i(x) T_i(T_s(x)),
// q_i = sum_r a[i][r] T_r.  a[i][r] = 2c[is+r] - a[i+1][s-r] (a[i][0]=c[is]);
// a[0][r] = c[r] - 0.5 a[1][s-r]; a[0][0] = c[0].
__device__ void regroup_d(const double* c, float* outp, int s, int m) {
  double al[64];
  for (int i = m; i >= 1; i--)
    for (int r = 0; r < s; r++) {
      double v;
      if (r == 0) v = c[s * i];
      else v = 2.0 * c[s * i + r] - ((i == m) ? 0.0 : al[s * (i + 1) + (s - r)]);
      al[s * i + r] = v;
    }
  al[0] = c[0];
  for (int r = 1; r < s; r++) al[r] = c[r] - 0.5 * al[s + (s - r)];
  int tot = s * (m + 1);
  for (int j = 0; j < tot; j++) outp[j] = (float)al[j];
}

// Setup: per-step Chebyshev coefficients (128-node DCT in fp64) + barrier reset.
__global__ void setup_kernel(const float* __restrict__ wts) {
  const int k = blockIdx.x;
  const int lane = threadIdx.x;
  __shared__ double s_fv[128];
  __shared__ double s_c[64];
  const double PI = 3.14159265358979323846;
  if (k < 256) {
    double w0 = (double)wts[2 * k], w1 = (double)wts[2 * k + 1];
    double t = 1.0 / (1.0 + exp(w0 - w1));     // softmax(...)[:,1]
    double c0 = 0.5 * ((double)AS_ + (double)BS_), h0 = 0.5 * ((double)BS_ - (double)AS_);
    for (int i = lane; i < 128; i += 64) {
      double th = (i + 0.5) * PI / 128.0;
      double y = c0 + h0 * cos(th);
      s_fv[i] = pow(y, t);
    }
    __syncthreads();
    if (lane < 40) {
      double s = 0.0;
      for (int i = 0; i < 128; i++) {
        double th = (i + 0.5) * PI / 128.0;
        s += s_fv[i] * cos((double)lane * th);
      }
      s_c[lane] = s * ((lane == 0) ? 1.0 : 2.0) / 128.0;
    }
    __syncthreads();
    if (lane == 0) regroup_d(s_c, g_aS[k], 8, 4);
  } else {
    double c0 = 0.5 * ((double)AM + (double)BM), h0 = 0.5 * ((double)BM - (double)AM);
    for (int i = lane; i < 128; i += 64) {
      double th = (i + 0.5) * PI / 128.0;
      double y = c0 + h0 * cos(th);
      s_fv[i] = 1.0 / sqrt(y);
    }
    __syncthreads();
    if (lane < 12) {
      double s = 0.0;
      for (int i = 0; i < 128; i++) {
        double th = (i + 0.5) * PI / 128.0;
        s += s_fv[i] * cos((double)lane * th);
      }
      s_c[lane] = s * ((lane == 0) ? 1.0 : 2.0) / 128.0;
    }
    __syncthreads();
    if (lane == 0) {
      regroup_d(s_c, g_aM, 4, 2);
      g_c1.v = 0; g_gen = 0;
      for (int j = 0; j < 16; j++) g_c0[j].v = 0;
    }
  }
}

__global__ void __launch_bounds__(256) frechet_kernel(const float* __restrict__ f,
                                                      float* __restrict__ out) {
  __shared__ int s_gen;
  __shared__ float part[4][4][64][5];   // [matmul][wave][lane][reg(+pad)]
  const int tid = threadIdx.x, bid = blockIdx.x;
  const int lane = tid & 63, wave = tid >> 6;
  // XCD-aware tile map: XCD x covers a 4-row x 8-col tile cluster.
  const int xcd = bid & 7, j = bid >> 3;
  const int tr = ((xcd >> 1) * 4 + (j & 3)) * 16;   // tile row base
  const int tc = ((xcd & 1) * 8 + (j >> 2)) * 16;   // tile col base
  const int arow = tr + (lane & 15);                // A-fragment row (global)
  const int colg = tc + (lane & 15);                // C col = B-sym row (global)
  const int kbase = wave * 64 + ((lane >> 4) * 8);  // this wave's K sub-offset
  const int erow = tr + ((lane >> 4) * 4) + wave;   // epilogue element row
  const int eidx = erow * 256 + colg;
  const float dI = (erow == colg) ? 1.0f : 0.0f;
  if (tid == 0) s_gen = 0;
  __syncthreads();

  const float sM = 2.0f / (BM - AM), cM = 0.5f * (AM + BM);
  const float sS = 2.0f / (BS_ - AS_), cS = 0.5f * (AS_ + BS_);

  // Init: XM = sM*(I - cM*I); prefetch f_0 into bf16 planes.
  {
    int i0 = bid * 256 + tid;   // covers [0,65536) exactly once
    wrm(iXM, i0, ((i0 >> 8) == (i0 & 255)) ? sM * (1.0f - cM) : 0.0f);
    wrm(iFK, i0, f[i0]);
  }
  gridbar(bid, &s_gen);

  for (int k = 0; k < 256; k++) {
    const float* aS = g_aS[k];
    const float* aM = g_aM;

    // ---- ISQ = p(M) ~ M^{-1/2}: s=4, m=2, deg 11 ----
    { // r1: U2 = 2*XM*XM - I
      f32x4 p = mm64(iXM, iXM, arow, colg, kbase);
      putp(part, 0, wave, lane, p);
      __syncthreads();
      float a = getp(part, 0, lane, wave);
      wrm(iU2, eidx, 2.0f * a - dI);
    }
    gridbar(bid, &s_gen);
    { // r2: U3 (regs), U4 ; precompute q2 (CBA), Q1, Q0 combos
      f32x4 p3 = mm64(iXM, iU2, arow, colg, kbase);
      f32x4 p4 = mm64(iU2, iU2, arow, colg, kbase);
      putp(part, 0, wave, lane, p3);
      putp(part, 1, wave, lane, p4);
      __syncthreads();
      float a3 = getp(part, 0, lane, wave), a4 = getp(part, 1, lane, wave);
      float xm = rdm(iXM, eidx), u2 = rdm(iU2, eidx);
      float u3 = 2.0f * a3 - xm;
      wrm(iU4, eidx, 2.0f * a4 - dI);
      wrm(iCBA, eidx, aM[8] * dI + aM[9] * xm + aM[10] * u2 + aM[11] * u3);
      wrm(iQM1, eidx, aM[4] * dI + aM[5] * xm + aM[6] * u2 + aM[7] * u3);
      wrm(iQM0, eidx, aM[0] * dI + aM[1] * xm + aM[2] * u2 + aM[3] * u3);
    }
    gridbar(bid, &s_gen);
    { // r3: CBB = 2*U4*CBA + Q1
      f32x4 p = mm64(iU4, iCBA, arow, colg, kbase);
      putp(part, 0, wave, lane, p);
      __syncthreads();
      wrm(iCBB, eidx, 2.0f * getp(part, 0, lane, wave) + rdm(iQM1, eidx));
    }
    gridbar(bid, &s_gen);
    { // r4: ISQ = U4*CBB - CBA + Q0
      f32x4 p = mm64(iU4, iCBB, arow, colg, kbase);
      putp(part, 0, wave, lane, p);
      __syncthreads();
      wrm(iISQ, eidx, getp(part, 0, lane, wave) - rdm(iCBA, eidx) + rdm(iQM0, eidx));
    }
    gridbar(bid, &s_gen);
    { // r5: SQ = (1/sM)*XM*ISQ + cM*ISQ ; G = ISQ*FK
      f32x4 p = mm64(iXM, iISQ, arow, colg, kbase);
      f32x4 q = mm64(iISQ, iFK, arow, colg, kbase);
      putp(part, 0, wave, lane, p);
      putp(part, 1, wave, lane, q);
      __syncthreads();
      wrm(iSQ, eidx, getp(part, 0, lane, wave) * (1.0f / sM) + cM * rdm(iISQ, eidx));
      wrm(iG, eidx, getp(part, 1, lane, wave));
    }
    gridbar(bid, &s_gen);
    { // r6: XS = sS*(G*ISQ) - sS*cS*I
      f32x4 p = mm64(iG, iISQ, arow, colg, kbase);
      putp(part, 0, wave, lane, p);
      __syncthreads();
      wrm(iXS, eidx, sS * getp(part, 0, lane, wave) - sS * cS * dI);
    }
    gridbar(bid, &s_gen);

    // ---- P = p(S) ~ S^t: s=8, m=4, deg 39 ----
    { // r7: V2 = 2*XS*XS - I
      f32x4 p = mm64(iXS, iXS, arow, colg, kbase);
      putp(part, 0, wave, lane, p);
      __syncthreads();
      wrm(iV2, eidx, 2.0f * getp(part, 0, lane, wave) - dI);
    }
    gridbar(bid, &s_gen);
    { // r8: V3 = 2*XS*V2 - XS ; V4 = 2*V2*V2 - I
      f32x4 p = mm64(iXS, iV2, arow, colg, kbase);
      f32x4 q = mm64(iV2, iV2, arow, colg, kbase);
      putp(part, 0, wave, lane, p);
      putp(part, 1, wave, lane, q);
      __syncthreads();
      wrm(iV3, eidx, 2.0f * getp(part, 0, lane, wave) - rdm(iXS, eidx));
      wrm(iV4, eidx, 2.0f * getp(part, 1, lane, wave) - dI);
    }
    gridbar(bid, &s_gen);
    { // r9: V5..V7 (regs), V8 ; q4 (SBA) and Q3..Q0 combos ; prefetch f_{k+1}
      f32x4 p5 = mm64(iV2, iV3, arow, colg, kbase);
      f32x4 p6 = mm64(iV3, iV3, arow, colg, kbase);
      f32x4 p7 = mm64(iV3, iV4, arow, colg, kbase);
      f32x4 p8 = mm64(iV4, iV4, arow, colg, kbase);
      float fv = 0.0f;
      int i0 = bid * 256 + tid;
      if (k < 255) fv = f[(size_t)(k + 1) * 65536 + i0];
      putp(part, 0, wave, lane, p5);
      putp(part, 1, wave, lane, p6);
      putp(part, 2, wave, lane, p7);
      putp(part, 3, wave, lane, p8);
      __syncthreads();
      float a5 = getp(part, 0, lane, wave), a6 = getp(part, 1, lane, wave);
      float a7 = getp(part, 2, lane, wave), a8 = getp(part, 3, lane, wave);
      float xs = rdm(iXS, eidx), v2 = rdm(iV2, eidx), v3 = rdm(iV3, eidx), v4 = rdm(iV4, eidx);
      float v5 = 2.0f * a5 - xs;   // T5 = 2*T2*T3 - T1
      float v6 = 2.0f * a6 - dI;   // T6 = 2*T3*T3 - T0
      float v7 = 2.0f * a7 - xs;   // T7 = 2*T3*T4 - T1
      float v8 = 2.0f * a8 - dI;   // T8 = 2*T4*T4 - T0
      wrm(iV8, eidx, v8);
      wrm(iSBA, eidx, aS[32] * dI + aS[33] * xs + aS[34] * v2 + aS[35] * v3 +
                      aS[36] * v4 + aS[37] * v5 + aS[38] * v6 + aS[39] * v7);
      wrm(iQS3, eidx, aS[24] * dI + aS[25] * xs + aS[26] * v2 + aS[27] * v3 +
                      aS[28] * v4 + aS[29] * v5 + aS[30] * v6 + aS[31] * v7);
      wrm(iQS2, eidx, aS[16] * dI + aS[17] * xs + aS[18] * v2 + aS[19] * v3 +
                      aS[20] * v4 + aS[21] * v5 + aS[22] * v6 + aS[23] * v7);
      wrm(iQS1, eidx, aS[8] * dI + aS[9] * xs + aS[10] * v2 + aS[11] * v3 +
                      aS[12] * v4 + aS[13] * v5 + aS[14] * v6 + aS[15] * v7);
      wrm(iQS0, eidx, aS[0] * dI + aS[1] * xs + aS[2] * v2 + aS[3] * v3 +
                      aS[4] * v4 + aS[5] * v5 + aS[6] * v6 + aS[7] * v7);
      if (k < 255) wrm(iFK, i0, fv);
    }
    gridbar(bid, &s_gen);
    { // r10: b3 = 2*V8*b4 + Q3
      f32x4 p = mm64(iV8, iSBA, arow, colg, kbase);
      putp(part, 0, wave, lane, p);
      __syncthreads();
      wrm(iSBB, eidx, 2.0f * getp(part, 0, lane, wave) + rdm(iQS3, eidx));
    }
    gridbar(bid, &s_gen);
    { // r11: b2 = 2*V8*b3 - b4 + Q2
      f32x4 p = mm64(iV8, iSBB, arow, colg, kbase);
      putp(part, 0, wave, lane, p);
      __syncthreads();
      wrm(iSBC, eidx, 2.0f * getp(part, 0, lane, wave) - rdm(iSBA, eidx) + rdm(iQS2, eidx));
    }
    gridbar(bid, &s_gen);
    { // r12: b1 = 2*V8*b2 - b3 + Q1
      f32x4 p = mm64(iV8, iSBC, arow, colg, kbase);
      putp(part, 0, wave, lane, p);
      __syncthreads();
      wrm(iSBA, eidx, 2.0f * getp(part, 0, lane, wave) - rdm(iSBB, eidx) + rdm(iQS1, eidx));
    }
    gridbar(bid, &s_gen);
    { // r13: P = V8*b1 - b2 + Q0
      f32x4 p = mm64(iV8, iSBA, arow, colg, kbase);
      putp(part, 0, wave, lane, p);
      __syncthreads();
      wrm(iPP, eidx, getp(part, 0, lane, wave) - rdm(iSBC, eidx) + rdm(iQS0, eidx));
    }
    gridbar(bid, &s_gen);
    { // r14: HH = SQ*P
      f32x4 p = mm64(iSQ, iPP, arow, colg, kbase);
      putp(part, 0, wave, lane, p);
      __syncthreads();
      wrm(iHH, eidx, getp(part, 0, lane, wave));
    }
    gridbar(bid, &s_gen);
    { // r15: Mn = HH*SQ -> out[k] (fp32, NT); XM_next = sM*(Mn - cM*I)
      f32x4 p = mm64(iHH, iSQ, arow, colg, kbase);
      putp(part, 0, wave, lane, p);
      __syncthreads();
      float v = getp(part, 0, lane, wave);
      __builtin_nontemporal_store(v, out + (size_t)k * 65536 + eidx);
      wrm(iXM, eidx, sM * (v - cM * dI));
    }
    gridbar(bid, &s_gen);
  }
}

extern "C" void kernel_launch(void* const* d_in, const int* in_sizes, int n_in,
                              void* d_out, int out_size, void* d_ws, size_t ws_size,
                              hipStream_t stream) {
  (void)in_sizes; (void)n_in; (void)d_ws; (void)ws_size; (void)out_size;
  const float* f = (const float*)d_in[0];
  const float* w = (const float*)d_in[1];
  float* out = (float*)d_out;

  setup_kernel<<<dim3(257), dim3(64), 0, stream>>>(w);

  // Plain launch: 256 blocks x 256 threads on 256 CUs (>=2 blocks/CU capacity)
  // are all co-resident, so the hand-rolled agent-scope barrier is safe.
  frechet_kernel<<<dim3(NBLK), dim3(256), 0, stream>>>(f, out);
}

// Round 5
// 41098.651 us; speedup vs baseline: 2.3359x; 2.3359x over previous
//
#include <hip/hip_runtime.h>
#include <math.h>

// BatchFrechetMean: inductive geodesic mean of 256 SPD 256x256 matrices.
// Eigh-free: fixed-interval Chebyshev polynomial evaluation of M^{-1/2} and S^t,
// persistent kernel (64 blocks, plain launch, co-resident) + hand-rolled grid
// barrier. R5: barrier spins on RELAXED atomics (no per-poll buffer_inv) with a
// single release/acquire fence pair per crossing; monotonic padded counters;
// f_{k+1} prefetch into bf16 planes; NT out stores. Math identical to R3.
//
// Spectral bounds (provable): lambda(f) in [1, ~5.2] => lambda(M) in [1, 5.5],
// lambda(S) in [1/5.75, 5.75]. Approximation intervals with margin:
//   x^{-1/2} on [0.95, 5.75], deg 11 (s=4, m=2)  -> err ~3e-5
//   x^{t}    on [0.17, 5.90], deg 39 (s=8, m=4)  -> err ~1e-6
//
// Perf history: R2 naive fp32 130ms (latency-bound scalar B loads) ->
// R3 bf16 planes + sym-B row reads 60ms -> R4 256-block K-split 96ms
// (REGRESSION: acquire-spin invalidation storm scales with spinner count).

#define NBLK 64
#define AM 0.95f
#define BM 5.75f
#define AS_ 0.17f
#define BS_ 5.90f

typedef __attribute__((ext_vector_type(8))) short bf16x8;
typedef __attribute__((ext_vector_type(4))) float f32x4;

enum {
  iXM = 0, iU2, iU4, iCBA, iCBB, iQM1, iQM0, iISQ, iSQ, iG,
  iXS, iV2, iV3, iV4, iV8, iSBA, iSBB, iSBC, iQS3, iQS2, iQS1, iQS0, iPP, iHH,
  iFK, NBUF
};

// Matrices stored as bf16 hi+lo planes (value = hi + lo, ~2^-16 rel err).
__device__ __align__(16) short gHi[NBUF][65536];
__device__ __align__(16) short gLo[NBUF][65536];
__device__ float g_aS[256][40];   // per-step regrouped Cheb coeffs of x^{t_k}
__device__ float g_aM[12];        // regrouped Cheb coeffs of x^{-1/2}

struct __align__(128) Ctr { int v; int pad[31]; };  // one 128B line per counter
__device__ Ctr g_c0[8];           // level-1: one per XCD group (monotonic)
__device__ Ctr g_c1;              // level-2 (monotonic)
__device__ int g_gen;             // published generation

__device__ __forceinline__ short f2bf(float x) {
  unsigned u = __builtin_bit_cast(unsigned, x);
  unsigned r = (u + 0x7FFFu + ((u >> 16) & 1u)) >> 16;   // RNE to bf16
  return (short)(unsigned short)r;
}
__device__ __forceinline__ float bf2f(short h) {
  unsigned u = ((unsigned)(unsigned short)h) << 16;
  return __builtin_bit_cast(float, u);
}
__device__ __forceinline__ float rdm(int m, int idx) {
  return bf2f(gHi[m][idx]) + bf2f(gLo[m][idx]);
}
__device__ __forceinline__ void wrm(int m, int idx, float v) {
  short h = f2bf(v);
  gHi[m][idx] = h;
  gLo[m][idx] = f2bf(v - bf2f(h));
}

// C(arow, bcol) fragment of A*B; B symmetric -> read B by rows (dwordx4).
// Split hi/lo bf16: 3 MFMAs per K-chunk, ~1e-5 rel err per matmul.
__device__ __forceinline__ f32x4 mmbf(int Ai, int Bi, int arow, int bcol, int kq) {
  f32x4 acc = {0.0f, 0.0f, 0.0f, 0.0f};
  const short* ah = gHi[Ai] + arow * 256 + kq;
  const short* al = gLo[Ai] + arow * 256 + kq;
  const short* bh = gHi[Bi] + bcol * 256 + kq;
  const short* bl = gLo[Bi] + bcol * 256 + kq;
#pragma unroll
  for (int k0 = 0; k0 < 256; k0 += 32) {
    bf16x8 Ah = *(const bf16x8*)(ah + k0);
    bf16x8 Al = *(const bf16x8*)(al + k0);
    bf16x8 Bh = *(const bf16x8*)(bh + k0);
    bf16x8 Bl = *(const bf16x8*)(bl + k0);
    acc = __builtin_amdgcn_mfma_f32_16x16x32_bf16(Ah, Bh, acc, 0, 0, 0);
    acc = __builtin_amdgcn_mfma_f32_16x16x32_bf16(Al, Bh, acc, 0, 0, 0);
    acc = __builtin_amdgcn_mfma_f32_16x16x32_bf16(Ah, Bl, acc, 0, 0, 0);
  }
  return acc;
}

// Grid barrier: RELAXED spin (no per-poll cache inv) + one release fence at
// arrival and one acquire fence at exit. Monotonic counters (target 8n+7)
// avoid reset/reorder races. Two-level 8x8, level-1 grouped by XCD (bid&7).
__device__ __forceinline__ void gridbar(int bid, int* sgen) {
  __syncthreads();
  if (threadIdx.x == 0) {
    int n = *sgen;
    __builtin_amdgcn_fence(__ATOMIC_RELEASE, "agent");   // waitcnt + wbL2, once
    int tgt = 8 * n + 7;
    int v = __hip_atomic_fetch_add(&g_c0[bid & 7].v, 1, __ATOMIC_RELAXED,
                                   __HIP_MEMORY_SCOPE_AGENT);
    if (v == tgt) {
      int w = __hip_atomic_fetch_add(&g_c1.v, 1, __ATOMIC_RELAXED,
                                     __HIP_MEMORY_SCOPE_AGENT);
      if (w == tgt) {
        __hip_atomic_store(&g_gen, n + 1, __ATOMIC_RELAXED,
                           __HIP_MEMORY_SCOPE_AGENT);
      }
    }
    while (__hip_atomic_load(&g_gen, __ATOMIC_RELAXED,
                             __HIP_MEMORY_SCOPE_AGENT) <= n)
      __builtin_amdgcn_s_sleep(1);
    __builtin_amdgcn_fence(__ATOMIC_ACQUIRE, "agent");   // waitcnt + inv, once
    *sgen = n + 1;
  }
  __syncthreads();
}

// Chebyshev-PS regrouping: p = sum_j c_j T_j  ->  sum_i q_i(x) T_i(T_s(x)),
// q_i = sum_r a[i][r] T_r.  a[i][r] = 2c[is+r] - a[i+1][s-r] (a[i][0]=c[is]);
// a[0][r] = c[r] - 0.5 a[1][s-r]; a[0][0] = c[0].
__device__ void regroup_d(const double* c, float* outp, int s, int m) {
  double al[64];
  for (int i = m; i >= 1; i--)
    for (int r = 0; r < s; r++) {
      double v;
      if (r == 0) v = c[s * i];
      else v = 2.0 * c[s * i + r] - ((i == m) ? 0.0 : al[s * (i + 1) + (s - r)]);
      al[s * i + r] = v;
    }
  al[0] = c[0];
  for (int r = 1; r < s; r++) al[r] = c[r] - 0.5 * al[s + (s - r)];
  int tot = s * (m + 1);
  for (int j = 0; j < tot; j++) outp[j] = (float)al[j];
}

// Setup: per-step Chebyshev coefficients (128-node DCT in fp64) + barrier reset.
__global__ void setup_kernel(const float* __restrict__ wts) {
  const int k = blockIdx.x;
  const int lane = threadIdx.x;
  __shared__ double s_fv[128];
  __shared__ double s_c[64];
  const double PI = 3.14159265358979323846;
  if (k < 256) {
    double w0 = (double)wts[2 * k], w1 = (double)wts[2 * k + 1];
    double t = 1.0 / (1.0 + exp(w0 - w1));     // softmax(...)[:,1]
    double c0 = 0.5 * ((double)AS_ + (double)BS_), h0 = 0.5 * ((double)BS_ - (double)AS_);
    for (int i = lane; i < 128; i += 64) {
      double th = (i + 0.5) * PI / 128.0;
      double y = c0 + h0 * cos(th);
      s_fv[i] = pow(y, t);
    }
    __syncthreads();
    if (lane < 40) {
      double s = 0.0;
      for (int i = 0; i < 128; i++) {
        double th = (i + 0.5) * PI / 128.0;
        s += s_fv[i] * cos((double)lane * th);
      }
      s_c[lane] = s * ((lane == 0) ? 1.0 : 2.0) / 128.0;
    }
    __syncthreads();
    if (lane == 0) regroup_d(s_c, g_aS[k], 8, 4);
  } else {
    double c0 = 0.5 * ((double)AM + (double)BM), h0 = 0.5 * ((double)BM - (double)AM);
    for (int i = lane; i < 128; i += 64) {
      double th = (i + 0.5) * PI / 128.0;
      double y = c0 + h0 * cos(th);
      s_fv[i] = 1.0 / sqrt(y);
    }
    __syncthreads();
    if (lane < 12) {
      double s = 0.0;
      for (int i = 0; i < 128; i++) {
        double th = (i + 0.5) * PI / 128.0;
        s += s_fv[i] * cos((double)lane * th);
      }
      s_c[lane] = s * ((lane == 0) ? 1.0 : 2.0) / 128.0;
    }
    __syncthreads();
    if (lane == 0) {
      regroup_d(s_c, g_aM, 4, 2);
      g_c1.v = 0; g_gen = 0;
      for (int j = 0; j < 8; j++) g_c0[j].v = 0;
    }
  }
}

__global__ void __launch_bounds__(256) frechet_kernel(const float* __restrict__ f,
                                                      float* __restrict__ out) {
  __shared__ int s_gen;
  const int tid = threadIdx.x, bid = blockIdx.x;
  const int lane = tid & 63, wave = tid >> 6;
  const int tr = (bid >> 3) * 32, tc = (bid & 7) * 32;
  const int sr = (wave >> 1) * 16, sc = (wave & 1) * 16;
  const int arow = tr + sr + (lane & 15);     // A-fragment row (global)
  const int colg = tc + sc + (lane & 15);     // C col = B-sym row (global)
  const int kq = (lane >> 4) * 8;             // K sub-offset within chunk
  const int row0 = tr + sr + (lane >> 4) * 4; // C rows for acc[0..3]
  const int fbase = (bid * 256 + tid) * 4;    // 4 contiguous f elems / thread
  if (tid == 0) s_gen = 0;
  __syncthreads();

  const float sM = 2.0f / (BM - AM), cM = 0.5f * (AM + BM);
  const float sS = 2.0f / (BS_ - AS_), cS = 0.5f * (AS_ + BS_);

  // Init: XM = sM*(I - cM*I); stage f_0 into bf16 planes.
  {
    float4 f0 = *(const float4*)(f + fbase);
    float fv[4] = {f0.x, f0.y, f0.z, f0.w};
#pragma unroll
    for (int r = 0; r < 4; r++) {
      int i = fbase + r;
      wrm(iXM, i, ((i >> 8) == (i & 255)) ? sM * (1.0f - cM) : 0.0f);
      wrm(iFK, i, fv[r]);
    }
  }
  gridbar(bid, &s_gen);

  for (int k = 0; k < 256; k++) {
    const float* aS = g_aS[k];
    const float* aM = g_aM;

    // ---- ISQ = p(M) ~ M^{-1/2}: s=4, m=2, deg 11 ----
    { // r1: U2 = 2*XM*XM - I
      f32x4 a = mmbf(iXM, iXM, arow, colg, kq);
#pragma unroll
      for (int r = 0; r < 4; r++) {
        int row = row0 + r, idx = row * 256 + colg;
        wrm(iU2, idx, 2.0f * a[r] - ((row == colg) ? 1.0f : 0.0f));
      }
    }
    gridbar(bid, &s_gen);
    { // r2: U3 (regs), U4 ; precompute q2 (CBA), Q1, Q0 combos
      f32x4 a3 = mmbf(iXM, iU2, arow, colg, kq);
      f32x4 a4 = mmbf(iU2, iU2, arow, colg, kq);
#pragma unroll
      for (int r = 0; r < 4; r++) {
        int row = row0 + r, idx = row * 256 + colg;
        float dI = (row == colg) ? 1.0f : 0.0f;
        float xm = rdm(iXM, idx), u2 = rdm(iU2, idx);
        float u3 = 2.0f * a3[r] - xm;
        wrm(iU4, idx, 2.0f * a4[r] - dI);
        wrm(iCBA, idx, aM[8] * dI + aM[9] * xm + aM[10] * u2 + aM[11] * u3);
        wrm(iQM1, idx, aM[4] * dI + aM[5] * xm + aM[6] * u2 + aM[7] * u3);
        wrm(iQM0, idx, aM[0] * dI + aM[1] * xm + aM[2] * u2 + aM[3] * u3);
      }
    }
    gridbar(bid, &s_gen);
    { // r3: CBB = 2*U4*CBA + Q1
      f32x4 a = mmbf(iU4, iCBA, arow, colg, kq);
#pragma unroll
      for (int r = 0; r < 4; r++) {
        int idx = (row0 + r) * 256 + colg;
        wrm(iCBB, idx, 2.0f * a[r] + rdm(iQM1, idx));
      }
    }
    gridbar(bid, &s_gen);
    { // r4: ISQ = U4*CBB - CBA + Q0
      f32x4 a = mmbf(iU4, iCBB, arow, colg, kq);
#pragma unroll
      for (int r = 0; r < 4; r++) {
        int idx = (row0 + r) * 256 + colg;
        wrm(iISQ, idx, a[r] - rdm(iCBA, idx) + rdm(iQM0, idx));
      }
    }
    gridbar(bid, &s_gen);
    { // r5: SQ = (1/sM)*XM*ISQ + cM*ISQ ; G = ISQ*FK
      f32x4 a = mmbf(iXM, iISQ, arow, colg, kq);
      f32x4 b = mmbf(iISQ, iFK, arow, colg, kq);
#pragma unroll
      for (int r = 0; r < 4; r++) {
        int idx = (row0 + r) * 256 + colg;
        wrm(iSQ, idx, a[r] * (1.0f / sM) + cM * rdm(iISQ, idx));
        wrm(iG, idx, b[r]);
      }
    }
    gridbar(bid, &s_gen);
    { // r6: XS = sS*(G*ISQ) - sS*cS*I
      f32x4 a = mmbf(iG, iISQ, arow, colg, kq);
#pragma unroll
      for (int r = 0; r < 4; r++) {
        int row = row0 + r, idx = row * 256 + colg;
        wrm(iXS, idx, sS * a[r] - sS * cS * ((row == colg) ? 1.0f : 0.0f));
      }
    }
    gridbar(bid, &s_gen);

    // ---- P = p(S) ~ S^t: s=8, m=4, deg 39 ----
    { // r7: V2 = 2*XS*XS - I
      f32x4 a = mmbf(iXS, iXS, arow, colg, kq);
#pragma unroll
      for (int r = 0; r < 4; r++) {
        int row = row0 + r, idx = row * 256 + colg;
        wrm(iV2, idx, 2.0f * a[r] - ((row == colg) ? 1.0f : 0.0f));
      }
    }
    gridbar(bid, &s_gen);
    { // r8: V3 = 2*XS*V2 - XS ; V4 = 2*V2*V2 - I
      f32x4 a = mmbf(iXS, iV2, arow, colg, kq);
      f32x4 b = mmbf(iV2, iV2, arow, colg, kq);
#pragma unroll
      for (int r = 0; r < 4; r++) {
        int row = row0 + r, idx = row * 256 + colg;
        float dI = (row == colg) ? 1.0f : 0.0f;
        wrm(iV3, idx, 2.0f * a[r] - rdm(iXS, idx));
        wrm(iV4, idx, 2.0f * b[r] - dI);
      }
    }
    gridbar(bid, &s_gen);
    { // r9: V5..V7 (regs), V8 ; q4 (SBA), Q3..Q0 combos ; prefetch f_{k+1}
      float4 fq = (k < 255) ? *(const float4*)(f + (size_t)(k + 1) * 65536 + fbase)
                            : make_float4(0.f, 0.f, 0.f, 0.f);
      f32x4 a5 = mmbf(iV2, iV3, arow, colg, kq);
      f32x4 a6 = mmbf(iV3, iV3, arow, colg, kq);
      f32x4 a7 = mmbf(iV3, iV4, arow, colg, kq);
      f32x4 a8 = mmbf(iV4, iV4, arow, colg, kq);
#pragma unroll
      for (int r = 0; r < 4; r++) {
        int row = row0 + r, idx = row * 256 + colg;
        float dI = (row == colg) ? 1.0f : 0.0f;
        float xs = rdm(iXS, idx), v2 = rdm(iV2, idx), v3 = rdm(iV3, idx), v4 = rdm(iV4, idx);
        float v5 = 2.0f * a5[r] - xs;   // T5 = 2*T2*T3 - T1
        float v6 = 2.0f * a6[r] - dI;   // T6 = 2*T3*T3 - T0
        float v7 = 2.0f * a7[r] - xs;   // T7 = 2*T3*T4 - T1
        float v8 = 2.0f * a8[r] - dI;   // T8 = 2*T4*T4 - T0
        wrm(iV8, idx, v8);
        wrm(iSBA, idx, aS[32] * dI + aS[33] * xs + aS[34] * v2 + aS[35] * v3 +
                       aS[36] * v4 + aS[37] * v5 + aS[38] * v6 + aS[39] * v7);
        wrm(iQS3, idx, aS[24] * dI + aS[25] * xs + aS[26] * v2 + aS[27] * v3 +
                       aS[28] * v4 + aS[29] * v5 + aS[30] * v6 + aS[31] * v7);
        wrm(iQS2, idx, aS[16] * dI + aS[17] * xs + aS[18] * v2 + aS[19] * v3 +
                       aS[20] * v4 + aS[21] * v5 + aS[22] * v6 + aS[23] * v7);
        wrm(iQS1, idx, aS[8] * dI + aS[9] * xs + aS[10] * v2 + aS[11] * v3 +
                       aS[12] * v4 + aS[13] * v5 + aS[14] * v6 + aS[15] * v7);
        wrm(iQS0, idx, aS[0] * dI + aS[1] * xs + aS[2] * v2 + aS[3] * v3 +
                       aS[4] * v4 + aS[5] * v5 + aS[6] * v6 + aS[7] * v7);
      }
      if (k < 255) {
        float fv[4] = {fq.x, fq.y, fq.z, fq.w};
#pragma unroll
        for (int r = 0; r < 4; r++) wrm(iFK, fbase + r, fv[r]);
      }
    }
    gridbar(bid, &s_gen);
    { // r10: b3 = 2*V8*b4 + Q3
      f32x4 a = mmbf(iV8, iSBA, arow, colg, kq);
#pragma unroll
      for (int r = 0; r < 4; r++) {
        int idx = (row0 + r) * 256 + colg;
        wrm(iSBB, idx, 2.0f * a[r] + rdm(iQS3, idx));
      }
    }
    gridbar(bid, &s_gen);
    { // r11: b2 = 2*V8*b3 - b4 + Q2
      f32x4 a = mmbf(iV8, iSBB, arow, colg, kq);
#pragma unroll
      for (int r = 0; r < 4; r++) {
        int idx = (row0 + r) * 256 + colg;
        wrm(iSBC, idx, 2.0f * a[r] - rdm(iSBA, idx) + rdm(iQS2, idx));
      }
    }
    gridbar(bid, &s_gen);
    { // r12: b1 = 2*V8*b2 - b3 + Q1
      f32x4 a = mmbf(iV8, iSBC, arow, colg, kq);
#pragma unroll
      for (int r = 0; r < 4; r++) {
        int idx = (row0 + r) * 256 + colg;
        wrm(iSBA, idx, 2.0f * a[r] - rdm(iSBB, idx) + rdm(iQS1, idx));
      }
    }
    gridbar(bid, &s_gen);
    { // r13: P = V8*b1 - b2 + Q0
      f32x4 a = mmbf(iV8, iSBA, arow, colg, kq);
#pragma unroll
      for (int r = 0; r < 4; r++) {
        int idx = (row0 + r) * 256 + colg;
        wrm(iPP, idx, a[r] - rdm(iSBC, idx) + rdm(iQS0, idx));
      }
    }
    gridbar(bid, &s_gen);
    { // r14: HH = SQ*P
      f32x4 a = mmbf(iSQ, iPP, arow, colg, kq);
#pragma unroll
      for (int r = 0; r < 4; r++) {
        int idx = (row0 + r) * 256 + colg;
        wrm(iHH, idx, a[r]);
      }
    }
    gridbar(bid, &s_gen);
    { // r15: Mn = HH*SQ -> out[k] (fp32, NT); XM_next = sM*(Mn - cM*I)
      f32x4 a = mmbf(iHH, iSQ, arow, colg, kq);
      float* ok = out + (size_t)k * 65536;
#pragma unroll
      for (int r = 0; r < 4; r++) {
        int row = row0 + r, idx = row * 256 + colg;
        float dI = (row == colg) ? 1.0f : 0.0f;
        float v = a[r];
        __builtin_nontemporal_store(v, ok + idx);
        wrm(iXM, idx, sM * (v - cM * dI));
      }
    }
    gridbar(bid, &s_gen);
  }
}

extern "C" void kernel_launch(void* const* d_in, const int* in_sizes, int n_in,
                              void* d_out, int out_size, void* d_ws, size_t ws_size,
                              hipStream_t stream) {
  (void)in_sizes; (void)n_in; (void)d_ws; (void)ws_size; (void)out_size;
  const float* f = (const float*)d_in[0];
  const float* w = (const float*)d_in[1];
  float* out = (float*)d_out;

  setup_kernel<<<dim3(257), dim3(64), 0, stream>>>(w);

  // Plain (non-cooperative) launch: 64 blocks x 256 threads on 256 CUs is
  // trivially co-resident, so the hand-rolled agent-scope barrier is safe.
  frechet_kernel<<<dim3(NBLK), dim3(256), 0, stream>>>(f, out);
}